// Round 6
// baseline (247.265 us; speedup 1.0000x reference)
//
#include <hip/hip_runtime.h>
#include <math.h>

#define N_NODES 50000
#define N_EDGES 800000
#define E_TOT   850000     // edges + self-loops
#define HEADS   8
#define HID     32
#define C1      256        // HEADS*HID
#define OUTC    16
#define NEG     0.2f
#define NB1     196        // build blocks = ceil(N/256); co-resident (<=256 CUs)
#define NTH     (NB1 * 256)          // 50176 threads
#define EPT     17                   // ceil(E_TOT / NTH)

__device__ __forceinline__ float lrelu(float v) { return v > 0.0f ? v : NEG * v; }

__device__ __forceinline__ void gridbar(int* cntw, int* flagw) {
    __syncthreads();
    if (threadIdx.x == 0) {
        int prev = __hip_atomic_fetch_add(cntw, 1, __ATOMIC_ACQ_REL, __HIP_MEMORY_SCOPE_AGENT);
        if (prev == NB1 - 1)
            __hip_atomic_store(flagw, 1, __ATOMIC_RELEASE, __HIP_MEMORY_SCOPE_AGENT);
        else
            while (__hip_atomic_load(flagw, __ATOMIC_ACQUIRE, __HIP_MEMORY_SCOPE_AGENT) == 0)
                __builtin_amdgcn_s_sleep(8);
    }
    __syncthreads();
}

// ---- fused CSR build: xp pack + count(rank in regs) -> scan -> fill ----
// syncw[0..5] zeroed by host memset each launch.
__global__ __launch_bounds__(256) void k_build(
    const float* __restrict__ x, const int* __restrict__ ei,
    float4* __restrict__ xp, int* __restrict__ cnt, int* __restrict__ off,
    int* __restrict__ bsum, int* __restrict__ bpre, int* __restrict__ syncw,
    int* __restrict__ csr_src)
{
    int tid = threadIdx.x, bid = blockIdx.x;
    int gt = bid * 256 + tid;                 // 0..50175
    // phase 0: pack xp
    if (gt < N_NODES)
        xp[gt] = make_float4(x[gt * 3], x[gt * 3 + 1], x[gt * 3 + 2], 1.0f);
    // phase 1: count + rank (ranks stay in registers)
    int rk[EPT];
    #pragma unroll
    for (int k = 0; k < EPT; k++) {
        int e = gt + k * NTH;
        if (e < E_TOT) {
            int d = (e < N_EDGES) ? ei[N_EDGES + e] : (e - N_EDGES);
            rk[k] = atomicAdd(&cnt[d], 1);
        }
    }
    gridbar(&syncw[0], &syncw[1]);            // all counts done

    // phase 2: two-level exclusive scan (block bid owns nodes [bid*256, +256))
    __shared__ int s[256];
    __shared__ int sFlag;
    int i = bid * 256 + tid;
    int v = (i < N_NODES)
          ? __hip_atomic_load(&cnt[i], __ATOMIC_RELAXED, __HIP_MEMORY_SCOPE_AGENT) : 0;
    s[tid] = v;
    __syncthreads();
    for (int o = 1; o < 256; o <<= 1) {
        int t2 = (tid >= o) ? s[tid - o] : 0;
        __syncthreads();
        s[tid] += t2;
        __syncthreads();
    }
    int excl = s[tid] - v;
    int total = s[255];
    __syncthreads();
    if (tid == 0) {
        __hip_atomic_store(&bsum[bid], total, __ATOMIC_RELEASE, __HIP_MEMORY_SCOPE_AGENT);
        int prev = __hip_atomic_fetch_add(&syncw[2], 1, __ATOMIC_ACQ_REL, __HIP_MEMORY_SCOPE_AGENT);
        sFlag = (prev == NB1 - 1) ? 1 : 0;
    }
    __syncthreads();
    if (sFlag) {                              // last-arriving block scans partials
        int bv = (tid < NB1)
               ? __hip_atomic_load(&bsum[tid], __ATOMIC_ACQUIRE, __HIP_MEMORY_SCOPE_AGENT) : 0;
        s[tid] = bv;
        __syncthreads();
        for (int o = 1; o < 256; o <<= 1) {
            int t2 = (tid >= o) ? s[tid - o] : 0;
            __syncthreads();
            s[tid] += t2;
            __syncthreads();
        }
        if (tid < NB1)
            __hip_atomic_store(&bpre[tid], s[tid] - bv, __ATOMIC_RELEASE, __HIP_MEMORY_SCOPE_AGENT);
        __syncthreads();
        if (tid == 0)
            __hip_atomic_store(&syncw[3], 1, __ATOMIC_RELEASE, __HIP_MEMORY_SCOPE_AGENT);
    }
    if (tid == 0) {
        while (__hip_atomic_load(&syncw[3], __ATOMIC_ACQUIRE, __HIP_MEMORY_SCOPE_AGENT) == 0)
            __builtin_amdgcn_s_sleep(8);
        sFlag = __hip_atomic_load(&bpre[bid], __ATOMIC_ACQUIRE, __HIP_MEMORY_SCOPE_AGENT);
    }
    __syncthreads();
    int base = sFlag;
    if (i < N_NODES)
        __hip_atomic_store(&off[i], base + excl, __ATOMIC_RELAXED, __HIP_MEMORY_SCOPE_AGENT);
    if (i == 0)
        __hip_atomic_store(&off[N_NODES], E_TOT, __ATOMIC_RELAXED, __HIP_MEMORY_SCOPE_AGENT);
    gridbar(&syncw[4], &syncw[5]);            // all off[] visible

    // phase 3: fill (ranks still in regs; ei re-read is L2/L3-hot)
    #pragma unroll
    for (int k = 0; k < EPT; k++) {
        int e = gt + k * NTH;
        if (e < E_TOT) {
            int sN, d;
            if (e < N_EDGES) { sN = ei[e]; d = ei[N_EDGES + e]; }
            else             { sN = d = e - N_EDGES; }
            int o = __hip_atomic_load(&off[d], __ATOMIC_RELAXED, __HIP_MEMORY_SCOPE_AGENT);
            csr_src[o + rk[k]] = sN;
        }
    }
}

// ---- layer-1 aggregation: 8 lanes per dst (lane = head) ----
__global__ __launch_bounds__(256) void k_agg1(
    const int* __restrict__ off, const int* __restrict__ csr_src,
    const float4* __restrict__ xp,
    const float* __restrict__ W1,
    const float* __restrict__ att_s1, const float* __restrict__ att_d1,
    float4* __restrict__ xaccw)
{
    __shared__ float sAtt[48];               // As1[24] | Ad1[24], [k*8+h]
    int tid = threadIdx.x;
    if (tid < 48) {
        int q = tid & 7, k = (tid >> 3) % 3;
        bool isD = tid >= 24;
        const float* att = isD ? att_d1 : att_s1;
        float a = 0.0f;
        for (int c = 0; c < HID; c++)
            a = fmaf(W1[k * C1 + q * HID + c], att[q * HID + c], a);
        sAtt[(isD ? 24 : 0) + k * 8 + q] = a;
    }
    __syncthreads();
    int h = tid & 7;
    int dst = blockIdx.x * 32 + (tid >> 3);
    if (dst >= N_NODES) return;
    float s0 = sAtt[h],      s1 = sAtt[8 + h],  s2 = sAtt[16 + h];
    float d0 = sAtt[24 + h], d1 = sAtt[32 + h], d2 = sAtt[40 + h];
    float4 xd = xp[dst];
    float ad = xd.x * d0 + xd.y * d1 + xd.z * d2;
    int beg = off[dst], end = off[dst + 1];
    float a0 = 0.0f, a1 = 0.0f, a2 = 0.0f, a3 = 0.0f;
    int nfull = beg + ((end - beg) & ~7);
    for (int base = beg; base < nfull; base += 8) {
        int sm = csr_src[base + h];
        float4 xv = xp[sm];
        #pragma unroll
        for (int j = 0; j < 8; j++) {
            float vx = __shfl(xv.x, j, 8);
            float vy = __shfl(xv.y, j, 8);
            float vz = __shfl(xv.z, j, 8);
            float as = vx * s0 + vy * s1 + vz * s2;
            float p = __expf(lrelu(as + ad));
            a0 = fmaf(p, vx, a0);
            a1 = fmaf(p, vy, a1);
            a2 = fmaf(p, vz, a2);
            a3 += p;
        }
    }
    if (nfull < end) {
        int idx = nfull + h;
        int sm = (idx < end) ? csr_src[idx] : 0;
        float4 xv = xp[sm];
        int m = end - nfull;
        for (int j = 0; j < m; j++) {
            float vx = __shfl(xv.x, j, 8);
            float vy = __shfl(xv.y, j, 8);
            float vz = __shfl(xv.z, j, 8);
            float as = vx * s0 + vy * s1 + vz * s2;
            float p = __expf(lrelu(as + ad));
            a0 = fmaf(p, vx, a0);
            a1 = fmaf(p, vy, a1);
            a2 = fmaf(p, vz, a2);
            a3 += p;
        }
    }
    xaccw[dst * 8 + h] = make_float4(a0, a1, a2, a3);
}

// ---- fused finalize layer1 + layer2 transform (stride 260: 2-way banks = free) ----
__global__ __launch_bounds__(256) void k_fin1h2(
    const float4* __restrict__ xaccw, const float* __restrict__ W1,
    const float* __restrict__ b1, const float* __restrict__ W2,
    const float* __restrict__ att_s2, const float* __restrict__ att_d2,
    float* __restrict__ h2, float* __restrict__ a_s2, float* __restrict__ a_d2)
{
    __shared__ float sW1[3 * C1];
    __shared__ float sAux[3 * C1];       // b1 | As2 | Ad2
    __shared__ float sW2t[OUTC][260];
    __shared__ float sElu[16][260];
    int t = threadIdx.x;
    for (int i = t; i < 3 * C1; i += 256) sW1[i] = W1[i];
    sAux[t] = b1[t];
    {
        float as2 = 0.0f, ad2 = 0.0f;
        for (int j = 0; j < OUTC; j++) {
            float w = W2[t * OUTC + j];
            as2 = fmaf(w, att_s2[j], as2);
            ad2 = fmaf(w, att_d2[j], ad2);
        }
        sAux[C1 + t] = as2; sAux[2 * C1 + t] = ad2;
    }
    for (int i = t; i < C1 * OUTC; i += 256) {
        int k = i >> 4, j = i & 15;
        sW2t[j][k] = W2[i];
    }
    __syncthreads();
    int n = t >> 4, l = t & 15;
    int node = blockIdx.x * 16 + n;
    float as = 0.0f, ad = 0.0f;
    for (int i = 0; i < 16; i++) {
        int c = l + 16 * i;
        int h = c >> 5;
        float4 xa = xaccw[node * 8 + h];
        float z = (xa.x * sW1[c] + xa.y * sW1[C1 + c] + xa.z * sW1[2 * C1 + c])
                  / (xa.w + 1e-16f) + sAux[c];
        float e = z > 0.0f ? z : expm1f(z);
        sElu[n][c] = e;
        as = fmaf(e, sAux[C1 + c], as);
        ad = fmaf(e, sAux[2 * C1 + c], ad);
    }
    for (int o = 1; o < 16; o <<= 1) {
        as += __shfl_xor(as, o, 64);
        ad += __shfl_xor(ad, o, 64);
    }
    if (l == 0) { a_s2[node] = as; a_d2[node] = ad; }
    __syncthreads();
    const float4* e4 = (const float4*)&sElu[n][0];
    const float4* w4 = (const float4*)&sW2t[l][0];
    float acc = 0.0f;
    #pragma unroll 8
    for (int k = 0; k < 64; k++) {
        float4 a = e4[k], b = w4[k];
        acc = fmaf(a.x, b.x, fmaf(a.y, b.y, fmaf(a.z, b.z, fmaf(a.w, b.w, acc))));
    }
    h2[node * OUTC + l] = acc;
}

// ---- layer-2 aggregation: 16 lanes per dst (lane = channel) ----
__global__ __launch_bounds__(256) void k_agg2(
    const int* __restrict__ off, const int* __restrict__ csr_src,
    const float* __restrict__ a_s, const float* __restrict__ a_d,
    const float* __restrict__ h2, const float* __restrict__ bias,
    float* __restrict__ out)
{
    int tid = threadIdx.x;
    int c = tid & 15;
    int dst = blockIdx.x * 16 + (tid >> 4);
    if (dst >= N_NODES) return;
    int beg = off[dst], end = off[dst + 1];
    float ad = a_d[dst];
    float acc = 0.0f, denp = 0.0f;
    int nfull = beg + ((end - beg) & ~15);
    for (int base = beg; base < nfull; base += 16) {
        int sm = csr_src[base + c];
        float p = __expf(lrelu(a_s[sm] + ad));
        denp += p;
        #pragma unroll
        for (int j = 0; j < 16; j++) {
            int s = __shfl(sm, j, 16);
            float pj = __shfl(p, j, 16);
            acc = fmaf(pj, h2[s * OUTC + c], acc);
        }
    }
    if (nfull < end) {
        int idx = nfull + c;
        int sm = 0; float p = 0.0f;
        if (idx < end) { sm = csr_src[idx]; p = __expf(lrelu(a_s[sm] + ad)); }
        denp += p;
        int mm = end - nfull;
        for (int j = 0; j < mm; j++) {
            int s = __shfl(sm, j, 16);
            float pj = __shfl(p, j, 16);
            acc = fmaf(pj, h2[s * OUTC + c], acc);
        }
    }
    for (int o = 1; o < 16; o <<= 1) denp += __shfl_xor(denp, o, 16);
    out[dst * OUTC + c] = acc / (denp + 1e-16f) + bias[c];
}

extern "C" void kernel_launch(void* const* d_in, const int* in_sizes, int n_in,
                              void* d_out, int out_size, void* d_ws, size_t ws_size,
                              hipStream_t stream)
{
    (void)in_sizes; (void)n_in; (void)out_size; (void)ws_size;
    const float* x    = (const float*)d_in[0];
    const int*   ei   = (const int*)d_in[1];
    const float* W1   = (const float*)d_in[2];
    const float* as1w = (const float*)d_in[3];
    const float* ad1w = (const float*)d_in[4];
    const float* b1   = (const float*)d_in[5];
    const float* W2   = (const float*)d_in[6];
    const float* as2w = (const float*)d_in[7];
    const float* ad2w = (const float*)d_in[8];
    const float* b2   = (const float*)d_in[9];
    float* out = (float*)d_out;

    const long N = N_NODES;
    char* p = (char*)d_ws;
    auto alloc = [&](size_t elems) {          // 16B-aligned
        void* r = p; p += ((elems + 3) & ~(size_t)3) * 4; return r;
    };

    float4* xp      = (float4*)alloc(N * 4);
    float4* xaccw   = (float4*)alloc(N * HEADS * 4);
    int*   cnt      = (int*)alloc(N + 8);     // cnt[N] + syncw[6]
    int*   syncw    = cnt + N;
    int*   bsum     = (int*)alloc(256);
    int*   bpre     = (int*)alloc(256);
    int*   off      = (int*)alloc(N + 1);
    int*   csr_src  = (int*)alloc(E_TOT);
    float* h2v      = (float*)alloc(N * OUTC);
    float* a_s2     = (float*)alloc(N);
    float* a_d2     = (float*)alloc(N);

    hipMemsetAsync(cnt, 0, (size_t)(N + 8) * sizeof(int), stream);

    k_build<<<NB1, 256, 0, stream>>>(x, ei, xp, cnt, off, bsum, bpre, syncw, csr_src);
    k_agg1<<<(int)((N + 31) / 32), 256, 0, stream>>>(off, csr_src, xp, W1, as1w, ad1w, xaccw);
    k_fin1h2<<<(int)(N / 16), 256, 0, stream>>>(xaccw, W1, b1, W2, as2w, ad2w, h2v, a_s2, a_d2);
    k_agg2<<<(int)(N / 16), 256, 0, stream>>>(off, csr_src, a_s2, a_d2, h2v, b2, out);
}

// Round 7
// 199.434 us; speedup vs baseline: 1.2398x; 1.2398x over previous
//
#include <hip/hip_runtime.h>
#include <math.h>

#define N_NODES 50000
#define N_EDGES 800000
#define E_TOT   850000     // edges + self-loops
#define HEADS   8
#define HID     32
#define C1      256        // HEADS*HID
#define OUTC    16
#define NEG     0.2f
#define NB1     ((N_NODES + 255) / 256)   // scan blocks = 196

__device__ __forceinline__ float lrelu(float v) { return v > 0.0f ? v : NEG * v; }

// ---- setup: pack xp = (x0,x1,x2,1) + CSR count/rank (850K threads) ----
__global__ __launch_bounds__(256) void k_setup(
    const float* __restrict__ x, const int* __restrict__ ei,
    float4* __restrict__ xp, int* __restrict__ cnt, int* __restrict__ rank)
{
    int e = blockIdx.x * 256 + threadIdx.x;
    if (e < N_NODES)
        xp[e] = make_float4(x[e * 3], x[e * 3 + 1], x[e * 3 + 2], 1.0f);
    if (e < E_TOT) {
        int d = (e < N_EDGES) ? ei[N_EDGES + e] : (e - N_EDGES);
        rank[e] = atomicAdd(&cnt[d], 1);
    }
}

__global__ void k_scan1(const int* __restrict__ cnt, int* __restrict__ part,
                        int* __restrict__ bsum)
{
    __shared__ int s[256];
    int tid = threadIdx.x;
    int i = blockIdx.x * 256 + tid;
    int v = (i < N_NODES) ? cnt[i] : 0;
    s[tid] = v;
    __syncthreads();
    for (int o = 1; o < 256; o <<= 1) {
        int t = (tid >= o) ? s[tid - o] : 0;
        __syncthreads();
        s[tid] += t;
        __syncthreads();
    }
    if (i < N_NODES) part[i] = s[tid] - v;   // exclusive
    if (tid == 255) bsum[blockIdx.x] = s[255];
}

// ---- merged level-2 scan + combine: block bid sums bsum[0..bid) itself ----
__global__ void k_scan23(const int* __restrict__ part, const int* __restrict__ bsum,
                         int* __restrict__ off)
{
    __shared__ int sred[256];
    int tid = threadIdx.x, bid = blockIdx.x;
    int acc = 0;
    for (int t = tid; t < bid; t += 256) acc += bsum[t];
    sred[tid] = acc;
    __syncthreads();
    for (int o = 128; o > 0; o >>= 1) {
        if (tid < o) sred[tid] += sred[tid + o];
        __syncthreads();
    }
    int base = sred[0];
    int i = bid * 256 + tid;
    if (i < N_NODES) off[i] = part[i] + base;
    if (i == 0) off[N_NODES] = E_TOT;
}

// ---- fill: no atomics (rank precomputed) ----
__global__ void k_fill(const int* __restrict__ ei, const int* __restrict__ rank,
                       const int* __restrict__ off, int* __restrict__ csr_src)
{
    int e = blockIdx.x * blockDim.x + threadIdx.x;
    if (e >= E_TOT) return;
    int s, d;
    if (e < N_EDGES) { s = ei[e]; d = ei[N_EDGES + e]; } else { s = d = e - N_EDGES; }
    csr_src[off[d] + rank[e]] = s;
}

// ---- layer-1 aggregation: 16 lanes per dst, lane = head(0..7) x sub(0..1) ----
// 16 edges gathered in flight per batch; register double-buffer prefetches
// batch b+1's (csr, xp) during batch b's shfl/FMA chain.
__global__ __launch_bounds__(256) void k_agg1(
    const int* __restrict__ off, const int* __restrict__ csr_src,
    const float4* __restrict__ xp,
    const float* __restrict__ W1,
    const float* __restrict__ att_s1, const float* __restrict__ att_d1,
    float4* __restrict__ xaccw)
{
    __shared__ float sAtt[48];               // As1[24] | Ad1[24], [k*8+h]
    int tid = threadIdx.x;
    if (tid < 48) {
        int q = tid & 7, k = (tid >> 3) % 3;
        bool isD = tid >= 24;
        const float* att = isD ? att_d1 : att_s1;
        float a = 0.0f;
        for (int c = 0; c < HID; c++)
            a = fmaf(W1[k * C1 + q * HID + c], att[q * HID + c], a);
        sAtt[(isD ? 24 : 0) + k * 8 + q] = a;
    }
    __syncthreads();
    int l = tid & 15, h = l & 7, sub = l >> 3;
    int dst = blockIdx.x * 16 + (tid >> 4);   // grid = N/16 exact
    float s0 = sAtt[h],      s1 = sAtt[8 + h],  s2 = sAtt[16 + h];
    float d0 = sAtt[24 + h], d1 = sAtt[32 + h], d2 = sAtt[40 + h];
    float4 xd = xp[dst];
    float ad = xd.x * d0 + xd.y * d1 + xd.z * d2;
    int beg = off[dst], end = off[dst + 1];
    float a0 = 0.0f, a1 = 0.0f, a2 = 0.0f, a3 = 0.0f;
    int nb = (end - beg + 15) >> 4;
    // prefetch batch 0
    int idx = beg + l;
    int sm = csr_src[(idx < end) ? idx : beg];
    float4 xv = xp[sm];
    for (int b = 0; b < nb; b++) {
        int base = beg + (b << 4);
        float4 xc = xv;
        if (b + 1 < nb) {                     // prefetch next batch
            int nidx = base + 16 + l;
            sm = csr_src[(nidx < end) ? nidx : (base + 16)];
            xv = xp[sm];
        }
        int rem = end - base;
        int mlim = rem < 16 ? rem : 16;
        int jbeg = sub * 8;
        int jlim = jbeg + 8 < mlim ? jbeg + 8 : mlim;
        for (int j = jbeg; j < jlim; j++) {
            float vx = __shfl(xc.x, j, 16);
            float vy = __shfl(xc.y, j, 16);
            float vz = __shfl(xc.z, j, 16);
            float as = vx * s0 + vy * s1 + vz * s2;
            float p = __expf(lrelu(as + ad));
            a0 = fmaf(p, vx, a0);
            a1 = fmaf(p, vy, a1);
            a2 = fmaf(p, vz, a2);
            a3 += p;
        }
    }
    a0 += __shfl_xor(a0, 8, 16);
    a1 += __shfl_xor(a1, 8, 16);
    a2 += __shfl_xor(a2, 8, 16);
    a3 += __shfl_xor(a3, 8, 16);
    if (sub == 0) xaccw[dst * 8 + h] = make_float4(a0, a1, a2, a3);
}

// ---- fused finalize layer1 + layer2 transform (stride 260: 2-way banks free) ----
__global__ __launch_bounds__(256) void k_fin1h2(
    const float4* __restrict__ xaccw, const float* __restrict__ W1,
    const float* __restrict__ b1, const float* __restrict__ W2,
    const float* __restrict__ att_s2, const float* __restrict__ att_d2,
    float* __restrict__ h2, float* __restrict__ a_s2, float* __restrict__ a_d2)
{
    __shared__ float sW1[3 * C1];
    __shared__ float sAux[3 * C1];       // b1 | As2 | Ad2
    __shared__ float sW2t[OUTC][260];
    __shared__ float sElu[16][260];
    int t = threadIdx.x;
    for (int i = t; i < 3 * C1; i += 256) sW1[i] = W1[i];
    sAux[t] = b1[t];
    {
        float as2 = 0.0f, ad2 = 0.0f;
        for (int j = 0; j < OUTC; j++) {
            float w = W2[t * OUTC + j];
            as2 = fmaf(w, att_s2[j], as2);
            ad2 = fmaf(w, att_d2[j], ad2);
        }
        sAux[C1 + t] = as2; sAux[2 * C1 + t] = ad2;
    }
    for (int i = t; i < C1 * OUTC; i += 256) {
        int k = i >> 4, j = i & 15;
        sW2t[j][k] = W2[i];
    }
    __syncthreads();
    int n = t >> 4, l = t & 15;
    int node = blockIdx.x * 16 + n;
    float as = 0.0f, ad = 0.0f;
    for (int i = 0; i < 16; i++) {
        int c = l + 16 * i;
        int h = c >> 5;
        float4 xa = xaccw[node * 8 + h];
        float z = (xa.x * sW1[c] + xa.y * sW1[C1 + c] + xa.z * sW1[2 * C1 + c])
                  / (xa.w + 1e-16f) + sAux[c];
        float e = z > 0.0f ? z : expm1f(z);
        sElu[n][c] = e;
        as = fmaf(e, sAux[C1 + c], as);
        ad = fmaf(e, sAux[2 * C1 + c], ad);
    }
    for (int o = 1; o < 16; o <<= 1) {
        as += __shfl_xor(as, o, 64);
        ad += __shfl_xor(ad, o, 64);
    }
    if (l == 0) { a_s2[node] = as; a_d2[node] = ad; }
    __syncthreads();
    const float4* e4 = (const float4*)&sElu[n][0];
    const float4* w4 = (const float4*)&sW2t[l][0];
    float acc = 0.0f;
    #pragma unroll 8
    for (int k = 0; k < 64; k++) {
        float4 a = e4[k], b = w4[k];
        acc = fmaf(a.x, b.x, fmaf(a.y, b.y, fmaf(a.z, b.z, fmaf(a.w, b.w, acc))));
    }
    h2[node * OUTC + l] = acc;
}

// ---- layer-2 aggregation: 16 lanes per dst (lane = channel), prefetched ----
__global__ __launch_bounds__(256) void k_agg2(
    const int* __restrict__ off, const int* __restrict__ csr_src,
    const float* __restrict__ a_s, const float* __restrict__ a_d,
    const float* __restrict__ h2, const float* __restrict__ bias,
    float* __restrict__ out)
{
    int tid = threadIdx.x;
    int c = tid & 15;
    int dst = blockIdx.x * 16 + (tid >> 4);   // grid = N/16 exact
    int beg = off[dst], end = off[dst + 1];
    float ad = a_d[dst];
    float acc = 0.0f, denp = 0.0f;
    int nb = (end - beg + 15) >> 4;
    // prefetch batch 0
    int idx = beg + c;
    int sm = csr_src[(idx < end) ? idx : beg];
    float asv = a_s[sm];
    for (int b = 0; b < nb; b++) {
        int base = beg + (b << 4);
        int smc = sm; float asc = asv;
        bool valid = (base + c) < end;
        if (b + 1 < nb) {                     // prefetch next batch
            int nidx = base + 16 + c;
            sm = csr_src[(nidx < end) ? nidx : (base + 16)];
            asv = a_s[sm];
        }
        float p = valid ? __expf(lrelu(asc + ad)) : 0.0f;
        denp += p;
        int rem = end - base;
        int mlim = rem < 16 ? rem : 16;
        if (mlim == 16) {
            #pragma unroll
            for (int j = 0; j < 16; j++) {
                int s = __shfl(smc, j, 16);
                float pj = __shfl(p, j, 16);
                acc = fmaf(pj, h2[s * OUTC + c], acc);
            }
        } else {
            for (int j = 0; j < mlim; j++) {
                int s = __shfl(smc, j, 16);
                float pj = __shfl(p, j, 16);
                acc = fmaf(pj, h2[s * OUTC + c], acc);
            }
        }
    }
    for (int o = 1; o < 16; o <<= 1) denp += __shfl_xor(denp, o, 16);
    out[dst * OUTC + c] = acc / (denp + 1e-16f) + bias[c];
}

extern "C" void kernel_launch(void* const* d_in, const int* in_sizes, int n_in,
                              void* d_out, int out_size, void* d_ws, size_t ws_size,
                              hipStream_t stream)
{
    (void)in_sizes; (void)n_in; (void)out_size; (void)ws_size;
    const float* x    = (const float*)d_in[0];
    const int*   ei   = (const int*)d_in[1];
    const float* W1   = (const float*)d_in[2];
    const float* as1w = (const float*)d_in[3];
    const float* ad1w = (const float*)d_in[4];
    const float* b1   = (const float*)d_in[5];
    const float* W2   = (const float*)d_in[6];
    const float* as2w = (const float*)d_in[7];
    const float* ad2w = (const float*)d_in[8];
    const float* b2   = (const float*)d_in[9];
    float* out = (float*)d_out;

    const long N = N_NODES;
    char* p = (char*)d_ws;
    auto alloc = [&](size_t elems) {          // 16B-aligned
        void* r = p; p += ((elems + 3) & ~(size_t)3) * 4; return r;
    };

    float4* xp      = (float4*)alloc(N * 4);
    float4* xaccw   = (float4*)alloc(N * HEADS * 4);
    int*   cnt      = (int*)alloc(N);
    int*   part     = (int*)alloc(N);
    int*   off      = (int*)alloc(N + 1);
    int*   bsum     = (int*)alloc(256);
    int*   rank     = (int*)alloc(E_TOT);
    int*   csr_src  = (int*)alloc(E_TOT);
    float* h2v      = (float*)alloc(N * OUTC);
    float* a_s2     = (float*)alloc(N);
    float* a_d2     = (float*)alloc(N);

    hipMemsetAsync(cnt, 0, (size_t)N * sizeof(int), stream);

    k_setup<<<(E_TOT + 255) / 256, 256, 0, stream>>>(x, ei, xp, cnt, rank);
    k_scan1<<<NB1, 256, 0, stream>>>(cnt, part, bsum);
    k_scan23<<<NB1, 256, 0, stream>>>(part, bsum, off);
    k_fill<<<(E_TOT + 255) / 256, 256, 0, stream>>>(ei, rank, off, csr_src);

    k_agg1<<<(int)(N / 16), 256, 0, stream>>>(off, csr_src, xp, W1, as1w, ad1w, xaccw);
    k_fin1h2<<<(int)(N / 16), 256, 0, stream>>>(xaccw, W1, b1, W2, as2w, ad2w, h2v, a_s2, a_d2);
    k_agg2<<<(int)(N / 16), 256, 0, stream>>>(off, csr_src, a_s2, a_d2, h2v, b2, out);
}